// Round 19
// baseline (321.366 us; speedup 1.0000x reference)
//
#include <hip/hip_runtime.h>
#include <hip/hip_bf16.h>
#include <stdint.h>

typedef unsigned short u16;
typedef __attribute__((ext_vector_type(8))) __bf16 bf16x8;
typedef __attribute__((ext_vector_type(4))) float f32x4;
typedef __attribute__((ext_vector_type(16))) float f32x16;
typedef __attribute__((ext_vector_type(8))) unsigned short u16x8;
typedef __attribute__((ext_vector_type(4))) unsigned int u32x4;

static __device__ __forceinline__ u16 f2bf(float x) {
  __hip_bfloat16 h = __float2bfloat16(x);
  u16 u;
  __builtin_memcpy(&u, &h, 2);
  return u;
}

static __device__ __forceinline__ float fast_tanh(float x) {
  float e = __expf(2.0f * x);
  return 1.0f - 2.0f * __builtin_amdgcn_rcpf(e + 1.0f);
}

static __device__ __forceinline__ void gload_lds16(const void* g, void* l) {
  __builtin_amdgcn_global_load_lds(
      (const __attribute__((address_space(1))) unsigned int*)g,
      (__attribute__((address_space(3))) unsigned int*)l, 16, 0, 0);
}

// XOR swizzle for 128-B rows (reg-staged kernels)
static __device__ __forceinline__ int swz(int row, int byte_in_row) {
  return row * 128 + (byte_in_row ^ ((row & 7) << 4));
}

// ---------------------------------------------------------------------------
// K1 (R19): transpose + cast ONLY Wet/Wpt (the linears' dependency).
// blocks [0,640): Wet[n][k] = bf16(W_enc[k][n]);  [640,1280): Wpt.
// ---------------------------------------------------------------------------
__global__ __launch_bounds__(256) void transpose_ep_kernel(
    const float* __restrict__ W_enc, const float* __restrict__ W_pred,
    u16* __restrict__ Wet, u16* __restrict__ Wpt) {
  const int bid = blockIdx.x;
  const float* in;
  u16* out;
  int n;
  if (bid < 640) {
    in = W_enc; out = Wet; n = bid;
  } else {
    in = W_pred; out = Wpt; n = bid - 640;
  }
  for (int k = threadIdx.x; k < 512; k += 256) {
    out[(size_t)n * 512 + k] = f2bf(in[(size_t)k * 640 + n]);
  }
}

// ---------------------------------------------------------------------------
// K2 (R19): fused linears + Wjt transpose in ONE launch.
// blocks [0,160):   f = enc@W_enc + b_enc   (16 m-tiles x 10 n-tiles)
// blocks [160,240): g = pred@W_pred + b_pred (8 m-tiles x 10 n-tiles)
// blocks [240,1264): Wjt[n][k] = bf16(W_joint[k][n])  (independent work --
//   fills the CUs the 240 linear blocks leave idle; Wjt is first consumed
//   by the gemm, well after this launch).
// Linear body byte-identical to the proven linear_kernel.
// ---------------------------------------------------------------------------
__global__ __launch_bounds__(256) void linear2_wjt_kernel(
    const float* __restrict__ enc, const float* __restrict__ pred,
    const u16* __restrict__ Wet, const u16* __restrict__ Wpt,
    const float* __restrict__ b_enc, const float* __restrict__ b_pred,
    const float* __restrict__ W_joint, u16* __restrict__ Wjt,
    float* __restrict__ f, float* __restrict__ g) {
  const int bxg = blockIdx.x;
  if (bxg >= 240) {  // Wjt transpose path (no LDS, no MFMA)
    const int n = bxg - 240;
    for (int k = threadIdx.x; k < 640; k += 256) {
      Wjt[(size_t)n * 640 + k] = f2bf(W_joint[(size_t)k * 1024 + n]);
    }
    return;
  }
  const float* A;
  const u16* Wt;
  const float* bias;
  float* out;
  int bx;
  if (bxg < 160) {
    A = enc; Wt = Wet; bias = b_enc; out = f; bx = bxg;
  } else {
    A = pred; Wt = Wpt; bias = b_pred; out = g; bx = bxg - 160;
  }
  __shared__ u16 sA[64 * 64];
  __shared__ u16 sB[64 * 64];
  const int t = threadIdx.x;
  const int m0 = (bx / 10) * 64;
  const int n0 = (bx % 10) * 64;
  const int lane = t & 63, wid = t >> 6;
  const int wr = wid >> 1, wc = wid & 1;
  const int l15 = lane & 15, lk8 = (lane >> 4) << 3;

  const int srow = t >> 2;
  const int kc = (t & 3) << 4;

  f32x4 acc[2][2] = {};

  for (int k0 = 0; k0 < 512; k0 += 64) {
    {
      const float4* gp = (const float4*)(A + (size_t)(m0 + srow) * 512 + k0 + kc);
      u16 tmp[16];
#pragma unroll
      for (int i = 0; i < 4; ++i) {
        float4 v = gp[i];
        tmp[i * 4 + 0] = f2bf(v.x);
        tmp[i * 4 + 1] = f2bf(v.y);
        tmp[i * 4 + 2] = f2bf(v.z);
        tmp[i * 4 + 3] = f2bf(v.w);
      }
      *(u16x8*)((char*)sA + swz(srow, kc * 2)) = *(u16x8*)&tmp[0];
      *(u16x8*)((char*)sA + swz(srow, kc * 2 + 16)) = *(u16x8*)&tmp[8];
    }
    {
      const int off = (t & 3) << 5;
      const char* gsrc = (const char*)Wt + ((size_t)(n0 + srow) * 512 + k0) * 2 + off;
      u32x4 q0 = *(const u32x4*)gsrc;
      u32x4 q1 = *(const u32x4*)(gsrc + 16);
      *(u32x4*)((char*)sB + swz(srow, off)) = q0;
      *(u32x4*)((char*)sB + swz(srow, off + 16)) = q1;
    }
    __syncthreads();
#pragma unroll
    for (int kh = 0; kh < 2; ++kh) {
      const int kbyte = kh * 64 + lk8 * 2;
      bf16x8 av[2], bv[2];
#pragma unroll
      for (int mf = 0; mf < 2; ++mf)
        av[mf] = *(const bf16x8*)((char*)sA + swz(wr * 32 + mf * 16 + l15, kbyte));
#pragma unroll
      for (int nf = 0; nf < 2; ++nf)
        bv[nf] = *(const bf16x8*)((char*)sB + swz(wc * 32 + nf * 16 + l15, kbyte));
#pragma unroll
      for (int mf = 0; mf < 2; ++mf)
#pragma unroll
        for (int nf = 0; nf < 2; ++nf)
          acc[mf][nf] = __builtin_amdgcn_mfma_f32_16x16x32_bf16(
              av[mf], bv[nf], acc[mf][nf], 0, 0, 0);
    }
    __syncthreads();
  }

  const int r4 = (lane >> 4) << 2;
#pragma unroll
  for (int nf = 0; nf < 2; ++nf) {
    const int nc = n0 + wc * 32 + nf * 16 + l15;
    const float bjv = bias[nc];
#pragma unroll
    for (int mf = 0; mf < 2; ++mf) {
      const int mr = m0 + wr * 32 + mf * 16 + r4;
#pragma unroll
      for (int r = 0; r < 4; ++r)
        out[(size_t)(mr + r) * 640 + nc] = acc[mf][nf][r] + bjv;
    }
  }
}

// ---------------------------------------------------------------------------
// Joint materialize: joint[row][k] (bf16) = tanh(f[bt][k] + g[b][u][k])
// ---------------------------------------------------------------------------
__global__ __launch_bounds__(256) void joint_kernel(
    const float* __restrict__ f, const float* __restrict__ g,
    u16* __restrict__ joint, int m_base) {
  int idx = blockIdx.x * 256 + threadIdx.x;
  int row = idx / 80;
  int kc = (idx % 80) * 8;
  int m = m_base + row;
  int bt = m >> 7;
  int b = bt >> 8;
  int u = m & 127;
  const float4* fp = (const float4*)(f + (size_t)bt * 640 + kc);
  const float4* gp = (const float4*)(g + ((size_t)(b * 128 + u)) * 640 + kc);
  u16 tmp[8];
#pragma unroll
  for (int i = 0; i < 2; ++i) {
    float4 fv = fp[i];
    float4 gv = gp[i];
    tmp[i * 4 + 0] = f2bf(fast_tanh(fv.x + gv.x));
    tmp[i * 4 + 1] = f2bf(fast_tanh(fv.y + gv.y));
    tmp[i * 4 + 2] = f2bf(fast_tanh(fv.z + gv.z));
    tmp[i * 4 + 3] = f2bf(fast_tanh(fv.w + gv.w));
  }
  *(u16x8*)(joint + (size_t)row * 640 + kc) = *(u16x8*)&tmp[0];
}

// ---------------------------------------------------------------------------
// 256x256 2-phase pipelined GEMM (R12 config, byte-identical): 8 waves,
// 32x32x16 MFMA, dbuf 128 KiB, gload_lds w/ inverse-swizzled source,
// swizzled ds_read, m204 XCD swizzle, setprio, cached C-stores.
// ---------------------------------------------------------------------------
__global__ __launch_bounds__(512, 2) void gemm256_kernel(
    const u16* __restrict__ A,    // [R][640] bf16 (chunk of joint)
    const u16* __restrict__ Bt,   // [1024][640] bf16 (W_joint^T)
    const float* __restrict__ bias,
    float* __restrict__ out,      // [131072][1024]
    int m_base, int mtiles) {
  extern __shared__ char smem[];  // [2][A 32K | B 32K] = 131072 B
  const int t = threadIdx.x;
  const int lane = t & 63, wid = t >> 6;

  // T1: m204 bijective XCD-chunked swizzle
  const int nwg = mtiles * 4;
  const int bid = blockIdx.x;
  const int q = nwg >> 3, r = nwg & 7;
  const int xcd = bid & 7, local = bid >> 3;
  const int wgid = (xcd < r ? xcd * (q + 1) : r * (q + 1) + (xcd - r) * q) + local;
  const int mt = wgid >> 2, nt = wgid & 3;

  const int wr = wid >> 2, wc = wid & 3;  // wave-tile rows wr*128, cols wc*64
  const int l31 = lane & 31, hi = lane >> 5;
  const int rx = (lane & 7) << 4;         // read-side swizzle xor (row&7)<<4

  const int srow = t >> 3;                                 // 0..63
  const int xc = ((t & 7) ^ ((t >> 3) & 7)) << 4;          // source col xor (bytes)
  const u16* aSrc[4];
  const u16* bSrc[4];
#pragma unroll
  for (int j = 0; j < 4; ++j) {
    const int row = j * 64 + srow;
    aSrc[j] = A + (size_t)(mt * 256 + row) * 640 + (xc >> 1);
    bSrc[j] = Bt + (size_t)(nt * 256 + row) * 640 + (xc >> 1);
  }
  const int sdst = wid * 1024;  // wave-uniform LDS chunk offset within line

  f32x16 acc[4][2] = {};

  // prologue: stage K-tile 0 into buf0
#pragma unroll
  for (int j = 0; j < 4; ++j) {
    gload_lds16(aSrc[j], smem + j * 8192 + sdst);
    gload_lds16(bSrc[j], smem + 32768 + j * 8192 + sdst);
  }
  __syncthreads();

  for (int tt = 0; tt < 10; ++tt) {
    const int bufo = (tt & 1) * 65536;
    if (tt < 9) {  // issue next-tile stages BEFORE compute (overlap)
      const int ke = (tt + 1) * 64;
      const int nbufo = bufo ^ 65536;
#pragma unroll
      for (int j = 0; j < 4; ++j) {
        gload_lds16(aSrc[j] + ke, smem + nbufo + j * 8192 + sdst);
        gload_lds16(bSrc[j] + ke, smem + nbufo + 32768 + j * 8192 + sdst);
      }
    }
    const char* sA = smem + bufo;
    const char* sB = smem + bufo + 32768;
#pragma unroll
    for (int ks = 0; ks < 4; ++ks) {  // 4 k-steps of 16
      const int cb = (ks * 32 + (hi << 4)) ^ rx;  // byte col within 128-B row
      bf16x8 bv[2], av[4];
#pragma unroll
      for (int nn = 0; nn < 2; ++nn)
        bv[nn] = *(const bf16x8*)(sB + (wc * 64 + nn * 32 + l31) * 128 + cb);
#pragma unroll
      for (int mm = 0; mm < 4; ++mm)
        av[mm] = *(const bf16x8*)(sA + (wr * 128 + mm * 32 + l31) * 128 + cb);
      __builtin_amdgcn_s_setprio(1);
#pragma unroll
      for (int mm = 0; mm < 4; ++mm)
#pragma unroll
        for (int nn = 0; nn < 2; ++nn)
          acc[mm][nn] = __builtin_amdgcn_mfma_f32_32x32x16_bf16(
              av[mm], bv[nn], acc[mm][nn], 0, 0, 0);
      __builtin_amdgcn_s_setprio(0);
    }
    if (tt < 9) __syncthreads();  // drains vmcnt(0): next buf fully staged
  }

  // epilogue: C/D col=lane&31, row=(reg&3)+8*(reg>>2)+4*hi  [m74/m101]
#pragma unroll
  for (int nn = 0; nn < 2; ++nn) {
    const int v = nt * 256 + wc * 64 + nn * 32 + l31;
    const float bjv = bias[v];
#pragma unroll
    for (int mm = 0; mm < 4; ++mm) {
      const size_t mrow =
          (size_t)m_base + (size_t)mt * 256 + wr * 128 + mm * 32 + hi * 4;
#pragma unroll
      for (int reg = 0; reg < 16; ++reg) {
        const int row = (reg & 3) + 8 * (reg >> 2);
        out[(mrow + row) * 1024 + v] = acc[mm][nn][reg] + bjv;
      }
    }
  }
}

// ---------------------------------------------------------------------------
// Fallback (fused) if ws can't hold the joint buffer.
// ---------------------------------------------------------------------------
__global__ __launch_bounds__(512) void fused_joint_kernel(
    const float* __restrict__ f, const float* __restrict__ g,
    const u16* __restrict__ Wjt, const float* __restrict__ bj,
    float* __restrict__ out) {
  __shared__ u16 sA[128 * 64];
  __shared__ u16 sB[256 * 64];
  const int t = threadIdx.x;
  const int bt = blockIdx.x;
  const int b = bt >> 8;
  const int v0 = blockIdx.y << 8;
  const float* frow = f + (size_t)bt * 640;
  const float* gbase = g + (size_t)b * 128 * 640;

  const int lane = t & 63, wid = t >> 6;
  const int wr = wid >> 2, wc = wid & 3;
  const int l15 = lane & 15, lk8 = (lane >> 4) << 3;

  const int au = t >> 2;
  const int akc = (t & 3) << 4;
  const int bn = t >> 1;
  const int boff = (t & 1) << 6;

  f32x4 acc[4][4] = {};

  for (int k0 = 0; k0 < 640; k0 += 64) {
    {
      const float4* gp = (const float4*)(gbase + (size_t)au * 640 + k0 + akc);
      const float4* fp = (const float4*)(frow + k0 + akc);
      u16 tmp[16];
#pragma unroll
      for (int i = 0; i < 4; ++i) {
        float4 gv = gp[i];
        float4 fv = fp[i];
        tmp[i * 4 + 0] = f2bf(fast_tanh(gv.x + fv.x));
        tmp[i * 4 + 1] = f2bf(fast_tanh(gv.y + fv.y));
        tmp[i * 4 + 2] = f2bf(fast_tanh(gv.z + fv.z));
        tmp[i * 4 + 3] = f2bf(fast_tanh(gv.w + fv.w));
      }
      *(u16x8*)((char*)sA + swz(au, akc * 2)) = *(u16x8*)&tmp[0];
      *(u16x8*)((char*)sA + swz(au, akc * 2 + 16)) = *(u16x8*)&tmp[8];
    }
    {
      const char* gsrc = (const char*)Wjt + ((size_t)(v0 + bn) * 640 + k0) * 2 + boff;
#pragma unroll
      for (int i = 0; i < 4; ++i) {
        u32x4 qv = *(const u32x4*)(gsrc + i * 16);
        *(u32x4*)((char*)sB + swz(bn, boff + i * 16)) = qv;
      }
    }
    __syncthreads();
#pragma unroll
    for (int kh = 0; kh < 2; ++kh) {
      const int kbyte = kh * 64 + lk8 * 2;
      bf16x8 av[4], bv[4];
#pragma unroll
      for (int mf = 0; mf < 4; ++mf)
        av[mf] = *(const bf16x8*)((char*)sA + swz(wr * 64 + mf * 16 + l15, kbyte));
#pragma unroll
      for (int nf = 0; nf < 4; ++nf)
        bv[nf] = *(const bf16x8*)((char*)sB + swz(wc * 64 + nf * 16 + l15, kbyte));
#pragma unroll
      for (int mf = 0; mf < 4; ++mf)
#pragma unroll
        for (int nf = 0; nf < 4; ++nf)
          acc[mf][nf] = __builtin_amdgcn_mfma_f32_16x16x32_bf16(
              av[mf], bv[nf], acc[mf][nf], 0, 0, 0);
    }
    __syncthreads();
  }

  const int r4 = (lane >> 4) << 2;
#pragma unroll
  for (int nf = 0; nf < 4; ++nf) {
    const int v = v0 + wc * 64 + nf * 16 + l15;
    const float bjv = bj[v];
#pragma unroll
    for (int mf = 0; mf < 4; ++mf) {
      const int u = wr * 64 + mf * 16 + r4;
      const size_t o = ((size_t)bt * 128 + u) * 1024 + v;
#pragma unroll
      for (int rr = 0; rr < 4; ++rr)
        out[o + (size_t)rr * 1024] = acc[mf][nf][rr] + bjv;
    }
  }
}

extern "C" void kernel_launch(void* const* d_in, const int* in_sizes, int n_in,
                              void* d_out, int out_size, void* d_ws, size_t ws_size,
                              hipStream_t stream) {
  const float* enc = (const float*)d_in[0];
  const float* pred = (const float*)d_in[1];
  const float* W_enc = (const float*)d_in[2];
  const float* b_enc = (const float*)d_in[3];
  const float* W_pred = (const float*)d_in[4];
  const float* b_pred = (const float*)d_in[5];
  const float* W_joint = (const float*)d_in[6];
  const float* b_joint = (const float*)d_in[7];
  float* out = (float*)d_out;

  char* ws = (char*)d_ws;
  float* f = (float*)ws;                                   // 2621440 B
  float* gbuf = (float*)(ws + 2621440);                    // 1310720 B
  u16* Wet = (u16*)(ws + 2621440 + 1310720);               // 655360 B
  u16* Wpt = (u16*)(ws + 2621440 + 1310720 + 655360);      // 655360 B
  u16* Wjt = (u16*)(ws + 2621440 + 1310720 + 2 * 655360);  // 1310720 B
  const size_t fixed = 2621440 + 1310720 + 2 * 655360 + 1310720;  // 6553600
  u16* joint = (u16*)(ws + fixed);

  // R19: K1 = Wet/Wpt transpose only; K2 = linears + Wjt transpose fused
  // (Wjt work rides in the CUs the 240 linear blocks leave idle).
  transpose_ep_kernel<<<1280, 256, 0, stream>>>(W_enc, W_pred, Wet, Wpt);
  linear2_wjt_kernel<<<1264, 256, 0, stream>>>(enc, pred, Wet, Wpt, b_enc,
                                               b_pred, W_joint, Wjt, f, gbuf);

  const long TOTAL_M = 131072;
  long maxrows = ws_size > fixed ? (long)((ws_size - fixed) / 1280) : 0;
  maxrows &= ~255L;  // gemm256 needs multiples of 256 rows

  if (maxrows >= 16384) {
    (void)hipFuncSetAttribute((const void*)gemm256_kernel,
                              hipFuncAttributeMaxDynamicSharedMemorySize, 131072);
    // CH = 32768 rows (42 MB joint chunk): R12-proven optimum.
    long CH = maxrows < 32768 ? maxrows : 32768;
    for (long m0 = 0; m0 < TOTAL_M; m0 += CH) {
      long R = TOTAL_M - m0 < CH ? TOTAL_M - m0 : CH;
      int mtiles = (int)(R / 256);
      joint_kernel<<<(int)(R / 128) * 40, 256, 0, stream>>>(f, gbuf, joint, (int)m0);
      gemm256_kernel<<<mtiles * 4, 512, 131072, stream>>>(joint, Wjt, b_joint, out,
                                                          (int)m0, mtiles);
    }
  } else {
    fused_joint_kernel<<<dim3(1024, 4), 512, 0, stream>>>(f, gbuf, Wjt, b_joint, out);
  }
}

// Round 20
// 320.154 us; speedup vs baseline: 1.0038x; 1.0038x over previous
//
#include <hip/hip_runtime.h>
#include <hip/hip_bf16.h>
#include <stdint.h>

typedef unsigned short u16;
typedef __attribute__((ext_vector_type(8))) __bf16 bf16x8;
typedef __attribute__((ext_vector_type(4))) float f32x4;
typedef __attribute__((ext_vector_type(16))) float f32x16;
typedef __attribute__((ext_vector_type(8))) unsigned short u16x8;
typedef __attribute__((ext_vector_type(4))) unsigned int u32x4;

static __device__ __forceinline__ u16 f2bf(float x) {
  __hip_bfloat16 h = __float2bfloat16(x);
  u16 u;
  __builtin_memcpy(&u, &h, 2);
  return u;
}

static __device__ __forceinline__ float fast_tanh(float x) {
  float e = __expf(2.0f * x);
  return 1.0f - 2.0f * __builtin_amdgcn_rcpf(e + 1.0f);
}

static __device__ __forceinline__ void gload_lds16(const void* g, void* l) {
  __builtin_amdgcn_global_load_lds(
      (const __attribute__((address_space(1))) unsigned int*)g,
      (__attribute__((address_space(3))) unsigned int*)l, 16, 0, 0);
}

// XOR swizzle for 128-B rows (reg-staged kernels)
static __device__ __forceinline__ int swz(int row, int byte_in_row) {
  return row * 128 + (byte_in_row ^ ((row & 7) << 4));
}

// ---------------------------------------------------------------------------
// Fused transpose + cast for all three weight matrices (1 launch):
// blocks [0,640):  Wet[n][k]  = bf16(W_enc[k][n])   K=512  N=640
// blocks [640,1280): Wpt      = bf16(W_pred[k][n])  K=512  N=640
// blocks [1280,2304): Wjt     = bf16(W_joint[k][n]) K=640  N=1024
// ---------------------------------------------------------------------------
__global__ __launch_bounds__(256) void transpose_all_kernel(
    const float* __restrict__ W_enc, const float* __restrict__ W_pred,
    const float* __restrict__ W_joint, u16* __restrict__ Wet,
    u16* __restrict__ Wpt, u16* __restrict__ Wjt) {
  const int bid = blockIdx.x;
  const float* in;
  u16* out;
  int K, N, n;
  if (bid < 640) {
    in = W_enc; out = Wet; K = 512; N = 640; n = bid;
  } else if (bid < 1280) {
    in = W_pred; out = Wpt; K = 512; N = 640; n = bid - 640;
  } else {
    in = W_joint; out = Wjt; K = 640; N = 1024; n = bid - 1280;
  }
  for (int k = threadIdx.x; k < K; k += 256) {
    out[(size_t)n * K + k] = f2bf(in[(size_t)k * N + n]);
  }
}

// ---------------------------------------------------------------------------
// Fused linear (1 launch): blocks [0,160) compute f = enc@W_enc + b_enc
// (16 m-tiles x 10 n-tiles); blocks [160,240) compute g = pred@W_pred+b_pred
// (8 m-tiles x 10 n-tiles).
// ---------------------------------------------------------------------------
__global__ __launch_bounds__(256) void linear2_kernel(
    const float* __restrict__ enc, const float* __restrict__ pred,
    const u16* __restrict__ Wet, const u16* __restrict__ Wpt,
    const float* __restrict__ b_enc, const float* __restrict__ b_pred,
    float* __restrict__ f, float* __restrict__ g) {
  const int bxg = blockIdx.x;
  const float* A;
  const u16* Wt;
  const float* bias;
  float* out;
  int bx;
  if (bxg < 160) {
    A = enc; Wt = Wet; bias = b_enc; out = f; bx = bxg;
  } else {
    A = pred; Wt = Wpt; bias = b_pred; out = g; bx = bxg - 160;
  }
  __shared__ u16 sA[64 * 64];
  __shared__ u16 sB[64 * 64];
  const int t = threadIdx.x;
  const int m0 = (bx / 10) * 64;
  const int n0 = (bx % 10) * 64;
  const int lane = t & 63, wid = t >> 6;
  const int wr = wid >> 1, wc = wid & 1;
  const int l15 = lane & 15, lk8 = (lane >> 4) << 3;

  const int srow = t >> 2;
  const int kc = (t & 3) << 4;

  f32x4 acc[2][2] = {};

  for (int k0 = 0; k0 < 512; k0 += 64) {
    {
      const float4* gp = (const float4*)(A + (size_t)(m0 + srow) * 512 + k0 + kc);
      u16 tmp[16];
#pragma unroll
      for (int i = 0; i < 4; ++i) {
        float4 v = gp[i];
        tmp[i * 4 + 0] = f2bf(v.x);
        tmp[i * 4 + 1] = f2bf(v.y);
        tmp[i * 4 + 2] = f2bf(v.z);
        tmp[i * 4 + 3] = f2bf(v.w);
      }
      *(u16x8*)((char*)sA + swz(srow, kc * 2)) = *(u16x8*)&tmp[0];
      *(u16x8*)((char*)sA + swz(srow, kc * 2 + 16)) = *(u16x8*)&tmp[8];
    }
    {
      const int off = (t & 3) << 5;
      const char* gsrc = (const char*)Wt + ((size_t)(n0 + srow) * 512 + k0) * 2 + off;
      u32x4 q0 = *(const u32x4*)gsrc;
      u32x4 q1 = *(const u32x4*)(gsrc + 16);
      *(u32x4*)((char*)sB + swz(srow, off)) = q0;
      *(u32x4*)((char*)sB + swz(srow, off + 16)) = q1;
    }
    __syncthreads();
#pragma unroll
    for (int kh = 0; kh < 2; ++kh) {
      const int kbyte = kh * 64 + lk8 * 2;
      bf16x8 av[2], bv[2];
#pragma unroll
      for (int mf = 0; mf < 2; ++mf)
        av[mf] = *(const bf16x8*)((char*)sA + swz(wr * 32 + mf * 16 + l15, kbyte));
#pragma unroll
      for (int nf = 0; nf < 2; ++nf)
        bv[nf] = *(const bf16x8*)((char*)sB + swz(wc * 32 + nf * 16 + l15, kbyte));
#pragma unroll
      for (int mf = 0; mf < 2; ++mf)
#pragma unroll
        for (int nf = 0; nf < 2; ++nf)
          acc[mf][nf] = __builtin_amdgcn_mfma_f32_16x16x32_bf16(
              av[mf], bv[nf], acc[mf][nf], 0, 0, 0);
    }
    __syncthreads();
  }

  const int r4 = (lane >> 4) << 2;
#pragma unroll
  for (int nf = 0; nf < 2; ++nf) {
    const int nc = n0 + wc * 32 + nf * 16 + l15;
    const float bjv = bias[nc];
#pragma unroll
    for (int mf = 0; mf < 2; ++mf) {
      const int mr = m0 + wr * 32 + mf * 16 + r4;
#pragma unroll
      for (int r = 0; r < 4; ++r)
        out[(size_t)(mr + r) * 640 + nc] = acc[mf][nf][r] + bjv;
    }
  }
}

// ---------------------------------------------------------------------------
// Joint materialize: joint[row][k] (bf16) = tanh(f[bt][k] + g[b][u][k])
// (normal stores: the gemm consumes this soon after -> want it cached)
// ---------------------------------------------------------------------------
__global__ __launch_bounds__(256) void joint_kernel(
    const float* __restrict__ f, const float* __restrict__ g,
    u16* __restrict__ joint, int m_base) {
  int idx = blockIdx.x * 256 + threadIdx.x;
  int row = idx / 80;
  int kc = (idx % 80) * 8;
  int m = m_base + row;
  int bt = m >> 7;
  int b = bt >> 8;
  int u = m & 127;
  const float4* fp = (const float4*)(f + (size_t)bt * 640 + kc);
  const float4* gp = (const float4*)(g + ((size_t)(b * 128 + u)) * 640 + kc);
  u16 tmp[8];
#pragma unroll
  for (int i = 0; i < 2; ++i) {
    float4 fv = fp[i];
    float4 gv = gp[i];
    tmp[i * 4 + 0] = f2bf(fast_tanh(fv.x + gv.x));
    tmp[i * 4 + 1] = f2bf(fast_tanh(fv.y + gv.y));
    tmp[i * 4 + 2] = f2bf(fast_tanh(fv.z + gv.z));
    tmp[i * 4 + 3] = f2bf(fast_tanh(fv.w + gv.w));
  }
  *(u16x8*)(joint + (size_t)row * 640 + kc) = *(u16x8*)&tmp[0];
}

// ---------------------------------------------------------------------------
// 256x256 2-phase pipelined GEMM (R12 config): 8 waves, 32x32x16 MFMA,
// dbuf 128 KiB, gload_lds w/ inverse-swizzled source, swizzled ds_read,
// m204 XCD swizzle, setprio, cached C-stores.
// ---------------------------------------------------------------------------
__global__ __launch_bounds__(512, 2) void gemm256_kernel(
    const u16* __restrict__ A,    // [R][640] bf16 (chunk of joint)
    const u16* __restrict__ Bt,   // [1024][640] bf16 (W_joint^T)
    const float* __restrict__ bias,
    float* __restrict__ out,      // [131072][1024]
    int m_base, int mtiles) {
  extern __shared__ char smem[];  // [2][A 32K | B 32K] = 131072 B
  const int t = threadIdx.x;
  const int lane = t & 63, wid = t >> 6;

  // T1: m204 bijective XCD-chunked swizzle
  const int nwg = mtiles * 4;
  const int bid = blockIdx.x;
  const int q = nwg >> 3, r = nwg & 7;
  const int xcd = bid & 7, local = bid >> 3;
  const int wgid = (xcd < r ? xcd * (q + 1) : r * (q + 1) + (xcd - r) * q) + local;
  const int mt = wgid >> 2, nt = wgid & 3;

  const int wr = wid >> 2, wc = wid & 3;  // wave-tile rows wr*128, cols wc*64
  const int l31 = lane & 31, hi = lane >> 5;
  const int rx = (lane & 7) << 4;         // read-side swizzle xor (row&7)<<4

  const int srow = t >> 3;                                 // 0..63
  const int xc = ((t & 7) ^ ((t >> 3) & 7)) << 4;          // source col xor (bytes)
  const u16* aSrc[4];
  const u16* bSrc[4];
#pragma unroll
  for (int j = 0; j < 4; ++j) {
    const int row = j * 64 + srow;
    aSrc[j] = A + (size_t)(mt * 256 + row) * 640 + (xc >> 1);
    bSrc[j] = Bt + (size_t)(nt * 256 + row) * 640 + (xc >> 1);
  }
  const int sdst = wid * 1024;  // wave-uniform LDS chunk offset within line

  f32x16 acc[4][2] = {};

  // prologue: stage K-tile 0 into buf0
#pragma unroll
  for (int j = 0; j < 4; ++j) {
    gload_lds16(aSrc[j], smem + j * 8192 + sdst);
    gload_lds16(bSrc[j], smem + 32768 + j * 8192 + sdst);
  }
  __syncthreads();

  for (int tt = 0; tt < 10; ++tt) {
    const int bufo = (tt & 1) * 65536;
    if (tt < 9) {  // issue next-tile stages BEFORE compute (overlap)
      const int ke = (tt + 1) * 64;
      const int nbufo = bufo ^ 65536;
#pragma unroll
      for (int j = 0; j < 4; ++j) {
        gload_lds16(aSrc[j] + ke, smem + nbufo + j * 8192 + sdst);
        gload_lds16(bSrc[j] + ke, smem + nbufo + 32768 + j * 8192 + sdst);
      }
    }
    const char* sA = smem + bufo;
    const char* sB = smem + bufo + 32768;
#pragma unroll
    for (int ks = 0; ks < 4; ++ks) {  // 4 k-steps of 16
      const int cb = (ks * 32 + (hi << 4)) ^ rx;  // byte col within 128-B row
      bf16x8 bv[2], av[4];
#pragma unroll
      for (int nn = 0; nn < 2; ++nn)
        bv[nn] = *(const bf16x8*)(sB + (wc * 64 + nn * 32 + l31) * 128 + cb);
#pragma unroll
      for (int mm = 0; mm < 4; ++mm)
        av[mm] = *(const bf16x8*)(sA + (wr * 128 + mm * 32 + l31) * 128 + cb);
      __builtin_amdgcn_s_setprio(1);
#pragma unroll
      for (int mm = 0; mm < 4; ++mm)
#pragma unroll
        for (int nn = 0; nn < 2; ++nn)
          acc[mm][nn] = __builtin_amdgcn_mfma_f32_32x32x16_bf16(
              av[mm], bv[nn], acc[mm][nn], 0, 0, 0);
      __builtin_amdgcn_s_setprio(0);
    }
    if (tt < 9) __syncthreads();  // drains vmcnt(0): next buf fully staged
  }

  // epilogue: C/D col=lane&31, row=(reg&3)+8*(reg>>2)+4*hi  [m74/m101]
#pragma unroll
  for (int nn = 0; nn < 2; ++nn) {
    const int v = nt * 256 + wc * 64 + nn * 32 + l31;
    const float bjv = bias[v];
#pragma unroll
    for (int mm = 0; mm < 4; ++mm) {
      const size_t mrow =
          (size_t)m_base + (size_t)mt * 256 + wr * 128 + mm * 32 + hi * 4;
#pragma unroll
      for (int reg = 0; reg < 16; ++reg) {
        const int row = (reg & 3) + 8 * (reg >> 2);
        out[(mrow + row) * 1024 + v] = acc[mm][nn][reg] + bjv;
      }
    }
  }
}

// ---------------------------------------------------------------------------
// Fallback (fused) if ws can't hold the joint buffer.
// ---------------------------------------------------------------------------
__global__ __launch_bounds__(512) void fused_joint_kernel(
    const float* __restrict__ f, const float* __restrict__ g,
    const u16* __restrict__ Wjt, const float* __restrict__ bj,
    float* __restrict__ out) {
  __shared__ u16 sA[128 * 64];
  __shared__ u16 sB[256 * 64];
  const int t = threadIdx.x;
  const int bt = blockIdx.x;
  const int b = bt >> 8;
  const int v0 = blockIdx.y << 8;
  const float* frow = f + (size_t)bt * 640;
  const float* gbase = g + (size_t)b * 128 * 640;

  const int lane = t & 63, wid = t >> 6;
  const int wr = wid >> 2, wc = wid & 3;
  const int l15 = lane & 15, lk8 = (lane >> 4) << 3;

  const int au = t >> 2;
  const int akc = (t & 3) << 4;
  const int bn = t >> 1;
  const int boff = (t & 1) << 6;

  f32x4 acc[4][4] = {};

  for (int k0 = 0; k0 < 640; k0 += 64) {
    {
      const float4* gp = (const float4*)(gbase + (size_t)au * 640 + k0 + akc);
      const float4* fp = (const float4*)(frow + k0 + akc);
      u16 tmp[16];
#pragma unroll
      for (int i = 0; i < 4; ++i) {
        float4 gv = gp[i];
        float4 fv = fp[i];
        tmp[i * 4 + 0] = f2bf(fast_tanh(gv.x + fv.x));
        tmp[i * 4 + 1] = f2bf(fast_tanh(gv.y + fv.y));
        tmp[i * 4 + 2] = f2bf(fast_tanh(gv.z + fv.z));
        tmp[i * 4 + 3] = f2bf(fast_tanh(gv.w + fv.w));
      }
      *(u16x8*)((char*)sA + swz(au, akc * 2)) = *(u16x8*)&tmp[0];
      *(u16x8*)((char*)sA + swz(au, akc * 2 + 16)) = *(u16x8*)&tmp[8];
    }
    {
      const char* gsrc = (const char*)Wjt + ((size_t)(v0 + bn) * 640 + k0) * 2 + boff;
#pragma unroll
      for (int i = 0; i < 4; ++i) {
        u32x4 qv = *(const u32x4*)(gsrc + i * 16);
        *(u32x4*)((char*)sB + swz(bn, boff + i * 16)) = qv;
      }
    }
    __syncthreads();
#pragma unroll
    for (int kh = 0; kh < 2; ++kh) {
      const int kbyte = kh * 64 + lk8 * 2;
      bf16x8 av[4], bv[4];
#pragma unroll
      for (int mf = 0; mf < 4; ++mf)
        av[mf] = *(const bf16x8*)((char*)sA + swz(wr * 64 + mf * 16 + l15, kbyte));
#pragma unroll
      for (int nf = 0; nf < 4; ++nf)
        bv[nf] = *(const bf16x8*)((char*)sB + swz(wc * 64 + nf * 16 + l15, kbyte));
#pragma unroll
      for (int mf = 0; mf < 4; ++mf)
#pragma unroll
        for (int nf = 0; nf < 4; ++nf)
          acc[mf][nf] = __builtin_amdgcn_mfma_f32_16x16x32_bf16(
              av[mf], bv[nf], acc[mf][nf], 0, 0, 0);
    }
    __syncthreads();
  }

  const int r4 = (lane >> 4) << 2;
#pragma unroll
  for (int nf = 0; nf < 4; ++nf) {
    const int v = v0 + wc * 64 + nf * 16 + l15;
    const float bjv = bj[v];
#pragma unroll
    for (int mf = 0; mf < 4; ++mf) {
      const int u = wr * 64 + mf * 16 + r4;
      const size_t o = ((size_t)bt * 128 + u) * 1024 + v;
#pragma unroll
      for (int rr = 0; rr < 4; ++rr)
        out[o + (size_t)rr * 1024] = acc[mf][nf][rr] + bjv;
    }
  }
}

extern "C" void kernel_launch(void* const* d_in, const int* in_sizes, int n_in,
                              void* d_out, int out_size, void* d_ws, size_t ws_size,
                              hipStream_t stream) {
  const float* enc = (const float*)d_in[0];
  const float* pred = (const float*)d_in[1];
  const float* W_enc = (const float*)d_in[2];
  const float* b_enc = (const float*)d_in[3];
  const float* W_pred = (const float*)d_in[4];
  const float* b_pred = (const float*)d_in[5];
  const float* W_joint = (const float*)d_in[6];
  const float* b_joint = (const float*)d_in[7];
  float* out = (float*)d_out;

  char* ws = (char*)d_ws;
  float* f = (float*)ws;                                   // 2621440 B
  float* gbuf = (float*)(ws + 2621440);                    // 1310720 B
  u16* Wet = (u16*)(ws + 2621440 + 1310720);               // 655360 B
  u16* Wpt = (u16*)(ws + 2621440 + 1310720 + 655360);      // 655360 B
  u16* Wjt = (u16*)(ws + 2621440 + 1310720 + 2 * 655360);  // 1310720 B
  const size_t fixed = 2621440 + 1310720 + 2 * 655360 + 1310720;  // 6553600
  u16* joint = (u16*)(ws + fixed);

  // Consolidated prologue -- 1 transpose launch + 1 linear launch (R18 best)
  transpose_all_kernel<<<2304, 256, 0, stream>>>(W_enc, W_pred, W_joint,
                                                 Wet, Wpt, Wjt);
  linear2_kernel<<<240, 256, 0, stream>>>(enc, pred, Wet, Wpt, b_enc, b_pred,
                                          f, gbuf);

  const long TOTAL_M = 131072;
  long maxrows = ws_size > fixed ? (long)((ws_size - fixed) / 1280) : 0;
  maxrows &= ~255L;  // gemm256 needs multiples of 256 rows

  if (maxrows >= 16384) {
    (void)hipFuncSetAttribute((const void*)gemm256_kernel,
                              hipFuncAttributeMaxDynamicSharedMemorySize, 131072);
    // CH = 32768 rows (42 MB joint chunk): R12-proven optimum.
    long CH = maxrows < 32768 ? maxrows : 32768;
    for (long m0 = 0; m0 < TOTAL_M; m0 += CH) {
      long R = TOTAL_M - m0 < CH ? TOTAL_M - m0 : CH;
      int mtiles = (int)(R / 256);
      joint_kernel<<<(int)(R / 128) * 40, 256, 0, stream>>>(f, gbuf, joint, (int)m0);
      gemm256_kernel<<<mtiles * 4, 512, 131072, stream>>>(joint, Wjt, b_joint, out,
                                                          (int)m0, mtiles);
    }
  } else {
    fused_joint_kernel<<<dim3(1024, 4), 512, 0, stream>>>(f, gbuf, Wjt, b_joint, out);
  }
}